// Round 2
// baseline (299.635 us; speedup 1.0000x reference)
//
#include <hip/hip_runtime.h>
#include <hip/hip_bf16.h>
#include <float.h>

#define BB   32
#define PP   16384
#define NOBJ 50
#define NCLS 21
#define PBLK 64   // blocks of 256 priors per image (P/256)

// ---------------- workspace layout ----------------
// [0]       u64   bestprior[BB*NOBJ]   (12800 B) packed (iou_bits<<32)|(~p)
// [12800]   int   n_pos[BB]            (128 B)
// [12928]   double accum[3]            (24 B)  0:conf_pos 1:loc_sum 2:hard_neg
// [16384]   float overlap[BB*PP]       (2 MB)
// [+2MB]    int   objfor[BB*PP]        (2 MB)
// [+4MB]    float neg[BB*PP]           (2 MB)

__global__ void k_init(unsigned long long* __restrict__ bestprior,
                       int* __restrict__ n_pos, double* __restrict__ accum) {
    int i = blockIdx.x * 256 + threadIdx.x;
    if (i < BB * NOBJ) bestprior[i] = 0xFFFFFFFFull;  // iou=0, prior=0
    if (i < BB) n_pos[i] = 0;
    if (i < 3) accum[i] = 0.0;
}

__global__ __launch_bounds__(256) void k_overlap(
    const float* __restrict__ boxes, const float* __restrict__ priors,
    float* __restrict__ overlap, int* __restrict__ objfor,
    unsigned long long* __restrict__ bestprior)
{
#pragma clang fp contract(off)
    const int b  = (int)blockIdx.x >> 6;
    const int p0 = ((int)blockIdx.x & 63) << 8;
    const int t  = (int)threadIdx.x;
    const int p  = p0 + t;

    __shared__ float4 sbox[NOBJ];
    __shared__ float  sarea[NOBJ];
    __shared__ unsigned long long sbest[NOBJ];

    if (t < NOBJ) {
        float4 bx = reinterpret_cast<const float4*>(boxes)[b * NOBJ + t];
        sbox[t]  = bx;
        sarea[t] = (bx.z - bx.x) * (bx.w - bx.y);
        sbest[t] = 0xFFFFFFFFull;   // iou=0, prior=0 (matches global init)
    }
    __syncthreads();

    float4 pc = reinterpret_cast<const float4*>(priors)[p];
    float hx = pc.z / 2.0f, hy = pc.w / 2.0f;
    float px0 = pc.x - hx, py0 = pc.y - hy;
    float px1 = pc.x + hx, py1 = pc.y + hy;
    float areab = (px1 - px0) * (py1 - py0);

    const unsigned long long myinv =
        (unsigned long long)(0xFFFFFFFFu - (unsigned)p);

    float best = -1.0f; int bestn = 0;
    for (int n = 0; n < NOBJ; ++n) {
        float4 bx = sbox[n];
        float ltx = fmaxf(bx.x, px0), lty = fmaxf(bx.y, py0);
        float rbx = fminf(bx.z, px1), rby = fminf(bx.w, py1);
        float dx = rbx - ltx; dx = dx > 0.0f ? dx : 0.0f;
        float dy = rby - lty; dy = dy > 0.0f ? dy : 0.0f;
        float inter = dx * dy;
        float iou = inter / ((sarea[n] + areab) - inter);
        if (iou > best) { best = iou; bestn = n; }   // first-max wins (strict >)
        // per-object best prior: read-prefiltered LDS atomicMax (benign race:
        // stale read only causes a redundant atomic)
        unsigned long long key =
            ((unsigned long long)__float_as_uint(iou) << 32) | myinv;
        if (key > sbest[n]) atomicMax(&sbest[n], key);
    }
    overlap[b * PP + p] = best;
    objfor[b * PP + p]  = bestn;
    __syncthreads();

    if (t < NOBJ) {
        unsigned long long k2 = sbest[t];
        if (k2 > 0xFFFFFFFFull)                      // block saw a positive iou
            atomicMax(&bestprior[b * NOBJ + t], k2);
    }
}

__global__ void k_force(const unsigned long long* __restrict__ bestprior,
                        float* __restrict__ overlap, int* __restrict__ objfor) {
    int b = (int)threadIdx.x;
    if (b >= BB) return;
    for (int n = 0; n < NOBJ; ++n) {                 // ascending n -> last wins
        unsigned long long pk = bestprior[b * NOBJ + n];
        int p = (int)(0xFFFFFFFFu - (unsigned)(pk & 0xFFFFFFFFull));
        objfor[b * PP + p]  = n;
        overlap[b * PP + p] = 1.0f;
    }
}

__global__ __launch_bounds__(256) void k_main(
    const float* __restrict__ locs, const float* __restrict__ scores,
    const float* __restrict__ boxes, const int* __restrict__ labels,
    const float* __restrict__ priors, const float* __restrict__ overlap,
    const int* __restrict__ objfor, float* __restrict__ neg,
    int* __restrict__ n_pos, double* __restrict__ accum)
{
#pragma clang fp contract(off)
    const int b   = (int)blockIdx.x >> 6;
    const int p0  = ((int)blockIdx.x & 63) << 8;
    const int t   = (int)threadIdx.x;
    const int p   = p0 + t;
    const int idx = b * PP + p;

    // stage 256x21 scores tile via coalesced float4 loads (21504 B, 16B-aligned)
    __shared__ float sls[256 * NCLS];
    {
        const float4* gsc = reinterpret_cast<const float4*>(
            scores + (size_t)(b * PP + p0) * NCLS);
        float4* dls = reinterpret_cast<float4*>(sls);
#pragma unroll
        for (int i = 0; i < 6; ++i) {
            int j = i * 256 + t;
            if (j < (256 * NCLS) / 4) dls[j] = gsc[j];
        }
    }
    __syncthreads();

    const int   n = objfor[idx];
    const float v = overlap[idx];
    int lbl = labels[b * NOBJ + n];
    if (v < 0.5f) lbl = 0;
    const bool pos = (lbl != 0);

    float locl1 = 0.0f;
    if (pos) {
        float4 bx = reinterpret_cast<const float4*>(boxes)[b * NOBJ + n];
        float4 pr = reinterpret_cast<const float4*>(priors)[p];
        float cx = (bx.x + bx.z) / 2.0f;
        float cy = (bx.y + bx.w) / 2.0f;
        float w  = bx.z - bx.x, h = bx.w - bx.y;
        float gx = (cx - pr.x) / (pr.z / 10.0f);
        float gy = (cy - pr.y) / (pr.w / 10.0f);
        float gw = logf(w / pr.z) * 5.0f;
        float gh = logf(h / pr.w) * 5.0f;
        float4 pl = reinterpret_cast<const float4*>(locs)[idx];
        locl1 = fabsf(pl.x - gx) + fabsf(pl.y - gy) +
                fabsf(pl.z - gw) + fabsf(pl.w - gh);
    }

    // cross-entropy via log-softmax over 21 classes (from LDS; stride 21 vs
    // 32 banks is coprime -> 2-way aliasing only, free)
    float x[NCLS];
    float m = -FLT_MAX;
#pragma unroll
    for (int c = 0; c < NCLS; ++c) { x[c] = sls[t * NCLS + c]; m = fmaxf(m, x[c]); }
    float tgt = 0.0f;
#pragma unroll
    for (int c = 0; c < NCLS; ++c) tgt = (c == lbl) ? x[c] : tgt;
    float s = 0.0f;
#pragma unroll
    for (int c = 0; c < NCLS; ++c) s += expf(x[c] - m);
    float ce = (logf(s) + m) - tgt;

    neg[idx] = pos ? 0.0f : ce;

    // wave reductions -> atomics
    float cp = pos ? ce : 0.0f;
    unsigned long long bal = __ballot(pos);
    float s1 = cp, s2 = locl1;
    for (int o = 32; o > 0; o >>= 1) {
        s1 += __shfl_down(s1, o, 64);
        s2 += __shfl_down(s2, o, 64);
    }
    if ((threadIdx.x & 63) == 0) {
        int cnt = (int)__popcll(bal);
        if (cnt) atomicAdd(&n_pos[b], cnt);
        if (s1 != 0.0f) atomicAdd(&accum[0], (double)s1);
        if (s2 != 0.0f) atomicAdd(&accum[1], (double)s2);
    }
}

// exact sum of top-K of neg[b,:] via 4x8-bit radix select (ce >= 0 so
// float bit pattern is order-preserving as uint). All passes run from LDS.
__global__ __launch_bounds__(1024) void k_topk(
    const float* __restrict__ neg, const int* __restrict__ n_pos,
    double* __restrict__ accum)
{
    const int b = (int)blockIdx.x;
    const int t = (int)threadIdx.x;
    const int wid = t >> 6;

    __shared__ float sval[PP];                 // 64 KB staged image
    __shared__ unsigned shist[16 * 257];       // per-wave padded histograms
    __shared__ unsigned scomb[256];
    __shared__ unsigned s_bb, s_above;
    __shared__ float swave[16];

    // stage neg[b,:] coalesced
    {
        const float4* g = reinterpret_cast<const float4*>(neg + (size_t)b * PP);
        float4* d = reinterpret_cast<float4*>(sval);
#pragma unroll
        for (int i = 0; i < PP / 4 / 1024; ++i)
            d[i * 1024 + t] = g[i * 1024 + t];
    }

    long long K = 3LL * (long long)n_pos[b];
    if (K > PP) K = PP;
    unsigned remaining = (unsigned)K;
    unsigned prefix = 0, mask = 0;
    float mySum = 0.0f;
    __syncthreads();

    for (int shift = 24; shift >= 0; shift -= 8) {
        for (int i = t; i < 16 * 257; i += 1024) shist[i] = 0;
        __syncthreads();
#pragma unroll
        for (int i = 0; i < PP / 1024; ++i) {
            unsigned u = __float_as_uint(sval[i * 1024 + t]);
            if ((u & mask) == prefix)
                atomicAdd(&shist[wid * 257 + ((u >> shift) & 255u)], 1u);
        }
        __syncthreads();
        if (t < 256) {
            unsigned c = 0;
#pragma unroll
            for (int w = 0; w < 16; ++w) c += shist[w * 257 + t];
            scomb[t] = c;
        }
        __syncthreads();
        if (t == 0) {
            unsigned cum = 0, bb = 0, above = 0;
            for (int bin = 255; bin >= 0; --bin) {
                unsigned c = scomb[bin];
                if (cum + c >= remaining) { bb = (unsigned)bin; above = cum; break; }
                cum += c;
            }
            s_bb = bb; s_above = above;
        }
        __syncthreads();
        unsigned bb = s_bb;
#pragma unroll
        for (int i = 0; i < PP / 1024; ++i) {
            unsigned u = __float_as_uint(sval[i * 1024 + t]);
            if ((u & mask) == prefix && ((u >> shift) & 255u) > bb)
                mySum += __uint_as_float(u);
        }
        remaining -= s_above;
        prefix |= bb << shift;
        mask   |= 255u << shift;
        __syncthreads();
    }

    float s = mySum;
    for (int o = 32; o > 0; o >>= 1) s += __shfl_down(s, o, 64);
    if ((t & 63) == 0) swave[wid] = s;
    __syncthreads();
    if (t == 0) {
        float tot = 0.0f;
        for (int w = 0; w < 16; ++w) tot += swave[w];
        if (remaining) tot += (float)remaining * __uint_as_float(prefix);
        atomicAdd(&accum[2], (double)tot);
    }
}

__global__ void k_final(const int* __restrict__ n_pos,
                        const double* __restrict__ accum,
                        float* __restrict__ out) {
    if (threadIdx.x == 0 && blockIdx.x == 0) {
        int tot = 0;
        for (int b = 0; b < BB; ++b) tot += n_pos[b];
        double npt  = (double)tot;
        double conf = (accum[0] + accum[2]) / npt;
        double loc  = accum[1] / (npt * 4.0);
        out[0] = (float)(conf + loc);
    }
}

extern "C" void kernel_launch(void* const* d_in, const int* in_sizes, int n_in,
                              void* d_out, int out_size, void* d_ws, size_t ws_size,
                              hipStream_t stream) {
    const float* locs   = (const float*)d_in[0];
    const float* scores = (const float*)d_in[1];
    const float* boxes  = (const float*)d_in[2];
    const int*   labels = (const int*)d_in[3];
    const float* priors = (const float*)d_in[4];

    char* ws = (char*)d_ws;
    unsigned long long* bestprior = (unsigned long long*)ws;
    int*    n_pos   = (int*)(ws + 12800);
    double* accum   = (double*)(ws + 12928);
    float*  overlap = (float*)(ws + 16384);
    int*    objfor  = (int*)(ws + 16384 + (size_t)BB * PP * 4);
    float*  neg     = (float*)(ws + 16384 + (size_t)BB * PP * 8);
    float*  out     = (float*)d_out;

    hipLaunchKernelGGL(k_init,    dim3(7),         dim3(256),  0, stream,
                       bestprior, n_pos, accum);
    hipLaunchKernelGGL(k_overlap, dim3(BB * PBLK), dim3(256),  0, stream,
                       boxes, priors, overlap, objfor, bestprior);
    hipLaunchKernelGGL(k_force,   dim3(1),         dim3(64),   0, stream,
                       bestprior, overlap, objfor);
    hipLaunchKernelGGL(k_main,    dim3(BB * PBLK), dim3(256),  0, stream,
                       locs, scores, boxes, labels, priors, overlap, objfor,
                       neg, n_pos, accum);
    hipLaunchKernelGGL(k_topk,    dim3(BB),        dim3(1024), 0, stream,
                       neg, n_pos, accum);
    hipLaunchKernelGGL(k_final,   dim3(1),         dim3(64),   0, stream,
                       n_pos, accum, out);
}

// Round 3
// 169.388 us; speedup vs baseline: 1.7689x; 1.7689x over previous
//
#include <hip/hip_runtime.h>
#include <hip/hip_bf16.h>
#include <float.h>

#define BB   32
#define PP   16384
#define NOBJ 50
#define NCLS 21
#define PBLK 64   // blocks of 256 priors per image (P/256)
#define NBLK (BB * PBLK)

// ---------------- workspace layout ----------------
// [0]       u64   bestprior[BB*NOBJ]     (12800 B) packed (iou_bits<<32)|(~p)
// [12800]   int   n_pos[BB]              (128 B)
// [12928]   double accum[3]              (24 B)  0:conf_pos 1:loc_sum 2:hard_neg
// [16384]   float overlap[BB*PP]         (2 MB)
// [+2MB]    int   objfor[BB*PP]          (2 MB)
// [+4MB]    float neg[BB*PP]             (2 MB)
// [+6MB]    double pc_conf[NBLK]         (16 KB)
// [..]      double pc_loc[NBLK]          (16 KB)
// [..]      int    pc_npos[NBLK]         (8 KB)

__global__ void k_init(unsigned long long* __restrict__ bestprior,
                       double* __restrict__ accum) {
    int i = blockIdx.x * 256 + threadIdx.x;
    if (i < BB * NOBJ) bestprior[i] = 0xFFFFFFFFull;  // iou=0, prior=0
    if (i < 3) accum[i] = 0.0;
}

__global__ __launch_bounds__(256) void k_overlap(
    const float* __restrict__ boxes, const float* __restrict__ priors,
    float* __restrict__ overlap, int* __restrict__ objfor,
    unsigned long long* __restrict__ bestprior)
{
#pragma clang fp contract(off)
    const int b  = (int)blockIdx.x >> 6;
    const int p0 = ((int)blockIdx.x & 63) << 8;
    const int t  = (int)threadIdx.x;
    const int p  = p0 + t;

    __shared__ float4 sbox[NOBJ];
    __shared__ float  sarea[NOBJ];
    __shared__ unsigned long long sbest[NOBJ];

    if (t < NOBJ) {
        float4 bx = reinterpret_cast<const float4*>(boxes)[b * NOBJ + t];
        sbox[t]  = bx;
        sarea[t] = (bx.z - bx.x) * (bx.w - bx.y);
        sbest[t] = 0xFFFFFFFFull;   // iou=0, prior=0 (matches global init)
    }
    __syncthreads();

    float4 pc = reinterpret_cast<const float4*>(priors)[p];
    float hx = pc.z / 2.0f, hy = pc.w / 2.0f;
    float px0 = pc.x - hx, py0 = pc.y - hy;
    float px1 = pc.x + hx, py1 = pc.y + hy;
    float areab = (px1 - px0) * (py1 - py0);

    const unsigned long long myinv =
        (unsigned long long)(0xFFFFFFFFu - (unsigned)p);

    float best = -1.0f; int bestn = 0;
    for (int n = 0; n < NOBJ; ++n) {
        float4 bx = sbox[n];
        float ltx = fmaxf(bx.x, px0), lty = fmaxf(bx.y, py0);
        float rbx = fminf(bx.z, px1), rby = fminf(bx.w, py1);
        float dx = rbx - ltx; dx = dx > 0.0f ? dx : 0.0f;
        float dy = rby - lty; dy = dy > 0.0f ? dy : 0.0f;
        float inter = dx * dy;
        float iou = inter / ((sarea[n] + areab) - inter);
        if (iou > best) { best = iou; bestn = n; }   // first-max wins (strict >)
        // per-object best prior: in-register wave max-reduce, then ONE
        // prefiltered LDS atomic by lane 0 (max key = max iou, ties -> larger
        // inv -> smaller p, matching argmax first-occurrence)
        unsigned long long key =
            ((unsigned long long)__float_as_uint(iou) << 32) | myinv;
        for (int o = 32; o > 0; o >>= 1) {
            unsigned long long other = __shfl_down(key, o, 64);
            if (other > key) key = other;
        }
        if ((t & 63) == 0 && key > sbest[n]) atomicMax(&sbest[n], key);
    }
    overlap[b * PP + p] = best;
    objfor[b * PP + p]  = bestn;
    __syncthreads();

    if (t < NOBJ) {
        unsigned long long k2 = sbest[t];
        if (k2 > 0xFFFFFFFFull)                      // block saw a positive iou
            atomicMax(&bestprior[b * NOBJ + t], k2);
    }
}

__global__ void k_force(const unsigned long long* __restrict__ bestprior,
                        float* __restrict__ overlap, int* __restrict__ objfor) {
    int b = (int)threadIdx.x;
    if (b >= BB) return;
    for (int n = 0; n < NOBJ; ++n) {                 // ascending n -> last wins
        unsigned long long pk = bestprior[b * NOBJ + n];
        int p = (int)(0xFFFFFFFFu - (unsigned)(pk & 0xFFFFFFFFull));
        objfor[b * PP + p]  = n;
        overlap[b * PP + p] = 1.0f;
    }
}

__global__ __launch_bounds__(256) void k_main(
    const float* __restrict__ locs, const float* __restrict__ scores,
    const float* __restrict__ boxes, const int* __restrict__ labels,
    const float* __restrict__ priors, const float* __restrict__ overlap,
    const int* __restrict__ objfor, float* __restrict__ neg,
    double* __restrict__ pc_conf, double* __restrict__ pc_loc,
    int* __restrict__ pc_npos)
{
#pragma clang fp contract(off)
    const int b   = (int)blockIdx.x >> 6;
    const int p0  = ((int)blockIdx.x & 63) << 8;
    const int t   = (int)threadIdx.x;
    const int p   = p0 + t;
    const int idx = b * PP + p;

    // stage 256x21 scores tile via coalesced float4 loads (21504 B, 16B-aligned)
    __shared__ float sls[256 * NCLS];
    __shared__ double sconf[4], sloc[4];
    __shared__ int    snp[4];
    {
        const float4* gsc = reinterpret_cast<const float4*>(
            scores + (size_t)(b * PP + p0) * NCLS);
        float4* dls = reinterpret_cast<float4*>(sls);
#pragma unroll
        for (int i = 0; i < 6; ++i) {
            int j = i * 256 + t;
            if (j < (256 * NCLS) / 4) dls[j] = gsc[j];
        }
    }
    __syncthreads();

    const int   n = objfor[idx];
    const float v = overlap[idx];
    int lbl = labels[b * NOBJ + n];
    if (v < 0.5f) lbl = 0;
    const bool pos = (lbl != 0);

    float locl1 = 0.0f;
    if (pos) {
        float4 bx = reinterpret_cast<const float4*>(boxes)[b * NOBJ + n];
        float4 pr = reinterpret_cast<const float4*>(priors)[p];
        float cx = (bx.x + bx.z) / 2.0f;
        float cy = (bx.y + bx.w) / 2.0f;
        float w  = bx.z - bx.x, h = bx.w - bx.y;
        float gx = (cx - pr.x) / (pr.z / 10.0f);
        float gy = (cy - pr.y) / (pr.w / 10.0f);
        float gw = logf(w / pr.z) * 5.0f;
        float gh = logf(h / pr.w) * 5.0f;
        float4 pl = reinterpret_cast<const float4*>(locs)[idx];
        locl1 = fabsf(pl.x - gx) + fabsf(pl.y - gy) +
                fabsf(pl.z - gw) + fabsf(pl.w - gh);
    }

    // cross-entropy via log-softmax over 21 classes (from LDS; stride 21 vs
    // 32 banks is coprime -> 2-way aliasing only, free)
    float x[NCLS];
    float m = -FLT_MAX;
#pragma unroll
    for (int c = 0; c < NCLS; ++c) { x[c] = sls[t * NCLS + c]; m = fmaxf(m, x[c]); }
    float tgt = 0.0f;
#pragma unroll
    for (int c = 0; c < NCLS; ++c) tgt = (c == lbl) ? x[c] : tgt;
    float s = 0.0f;
#pragma unroll
    for (int c = 0; c < NCLS; ++c) s += expf(x[c] - m);
    float ce = (logf(s) + m) - tgt;

    neg[idx] = pos ? 0.0f : ce;

    // wave reductions -> per-block partials (NO global atomics)
    float cp = pos ? ce : 0.0f;
    unsigned long long bal = __ballot(pos);
    float s1 = cp, s2 = locl1;
    for (int o = 32; o > 0; o >>= 1) {
        s1 += __shfl_down(s1, o, 64);
        s2 += __shfl_down(s2, o, 64);
    }
    if ((t & 63) == 0) {
        int w = t >> 6;
        sconf[w] = (double)s1;
        sloc[w]  = (double)s2;
        snp[w]   = (int)__popcll(bal);
    }
    __syncthreads();
    if (t == 0) {
        pc_conf[blockIdx.x] = sconf[0] + sconf[1] + sconf[2] + sconf[3];
        pc_loc[blockIdx.x]  = sloc[0] + sloc[1] + sloc[2] + sloc[3];
        pc_npos[blockIdx.x] = snp[0] + snp[1] + snp[2] + snp[3];
    }
}

// blocks 0..BB-1: n_pos[b] = sum of that image's 64 block partials
// block BB: accum[0] = sum pc_conf, accum[1] = sum pc_loc
__global__ __launch_bounds__(256) void k_reduce(
    const double* __restrict__ pc_conf, const double* __restrict__ pc_loc,
    const int* __restrict__ pc_npos, int* __restrict__ n_pos,
    double* __restrict__ accum)
{
    const int t = (int)threadIdx.x;
    if ((int)blockIdx.x < BB) {
        const int b = (int)blockIdx.x;
        int v = (t < PBLK) ? pc_npos[b * PBLK + t] : 0;
        for (int o = 32; o > 0; o >>= 1) v += __shfl_down(v, o, 64);
        if (t == 0) n_pos[b] = v;
    } else {
        __shared__ double sa[4], sb[4];
        double a = 0.0, c = 0.0;
        for (int i = t; i < NBLK; i += 256) { a += pc_conf[i]; c += pc_loc[i]; }
        for (int o = 32; o > 0; o >>= 1) {
            a += __shfl_down(a, o, 64);
            c += __shfl_down(c, o, 64);
        }
        if ((t & 63) == 0) { sa[t >> 6] = a; sb[t >> 6] = c; }
        __syncthreads();
        if (t == 0) {
            accum[0] = sa[0] + sa[1] + sa[2] + sa[3];
            accum[1] = sb[0] + sb[1] + sb[2] + sb[3];
        }
    }
}

// exact sum of top-K of neg[b,:] via 4x8-bit radix select (ce >= 0 so
// float bit pattern is order-preserving as uint). All passes run from LDS.
__global__ __launch_bounds__(1024) void k_topk(
    const float* __restrict__ neg, const int* __restrict__ n_pos,
    double* __restrict__ accum)
{
    const int b = (int)blockIdx.x;
    const int t = (int)threadIdx.x;
    const int wid = t >> 6;

    __shared__ float sval[PP];                 // 64 KB staged image
    __shared__ unsigned shist[16 * 257];       // per-wave padded histograms
    __shared__ unsigned scomb[256];
    __shared__ unsigned s_bb, s_above;
    __shared__ float swave[16];

    // stage neg[b,:] coalesced
    {
        const float4* g = reinterpret_cast<const float4*>(neg + (size_t)b * PP);
        float4* d = reinterpret_cast<float4*>(sval);
#pragma unroll
        for (int i = 0; i < PP / 4 / 1024; ++i)
            d[i * 1024 + t] = g[i * 1024 + t];
    }

    long long K = 3LL * (long long)n_pos[b];
    if (K > PP) K = PP;
    unsigned remaining = (unsigned)K;
    unsigned prefix = 0, mask = 0;
    float mySum = 0.0f;
    __syncthreads();

    for (int shift = 24; shift >= 0; shift -= 8) {
        for (int i = t; i < 16 * 257; i += 1024) shist[i] = 0;
        __syncthreads();
#pragma unroll
        for (int i = 0; i < PP / 1024; ++i) {
            unsigned u = __float_as_uint(sval[i * 1024 + t]);
            if ((u & mask) == prefix)
                atomicAdd(&shist[wid * 257 + ((u >> shift) & 255u)], 1u);
        }
        __syncthreads();
        if (t < 256) {
            unsigned c = 0;
#pragma unroll
            for (int w = 0; w < 16; ++w) c += shist[w * 257 + t];
            scomb[t] = c;
        }
        __syncthreads();
        if (t == 0) {
            unsigned cum = 0, bb = 0, above = 0;
            for (int bin = 255; bin >= 0; --bin) {
                unsigned c = scomb[bin];
                if (cum + c >= remaining) { bb = (unsigned)bin; above = cum; break; }
                cum += c;
            }
            s_bb = bb; s_above = above;
        }
        __syncthreads();
        unsigned bb = s_bb;
#pragma unroll
        for (int i = 0; i < PP / 1024; ++i) {
            unsigned u = __float_as_uint(sval[i * 1024 + t]);
            if ((u & mask) == prefix && ((u >> shift) & 255u) > bb)
                mySum += __uint_as_float(u);
        }
        remaining -= s_above;
        prefix |= bb << shift;
        mask   |= 255u << shift;
        __syncthreads();
    }

    float s = mySum;
    for (int o = 32; o > 0; o >>= 1) s += __shfl_down(s, o, 64);
    if ((t & 63) == 0) swave[wid] = s;
    __syncthreads();
    if (t == 0) {
        float tot = 0.0f;
        for (int w = 0; w < 16; ++w) tot += swave[w];
        if (remaining) tot += (float)remaining * __uint_as_float(prefix);
        atomicAdd(&accum[2], (double)tot);   // 32 blocks total: negligible
    }
}

__global__ void k_final(const int* __restrict__ n_pos,
                        const double* __restrict__ accum,
                        float* __restrict__ out) {
    if (threadIdx.x == 0 && blockIdx.x == 0) {
        int tot = 0;
        for (int b = 0; b < BB; ++b) tot += n_pos[b];
        double npt  = (double)tot;
        double conf = (accum[0] + accum[2]) / npt;
        double loc  = accum[1] / (npt * 4.0);
        out[0] = (float)(conf + loc);
    }
}

extern "C" void kernel_launch(void* const* d_in, const int* in_sizes, int n_in,
                              void* d_out, int out_size, void* d_ws, size_t ws_size,
                              hipStream_t stream) {
    const float* locs   = (const float*)d_in[0];
    const float* scores = (const float*)d_in[1];
    const float* boxes  = (const float*)d_in[2];
    const int*   labels = (const int*)d_in[3];
    const float* priors = (const float*)d_in[4];

    char* ws = (char*)d_ws;
    unsigned long long* bestprior = (unsigned long long*)ws;
    int*    n_pos   = (int*)(ws + 12800);
    double* accum   = (double*)(ws + 12928);
    float*  overlap = (float*)(ws + 16384);
    int*    objfor  = (int*)(ws + 16384 + (size_t)BB * PP * 4);
    float*  neg     = (float*)(ws + 16384 + (size_t)BB * PP * 8);
    char*   ppart   = ws + 16384 + (size_t)BB * PP * 12;
    double* pc_conf = (double*)ppart;
    double* pc_loc  = (double*)(ppart + NBLK * 8);
    int*    pc_npos = (int*)(ppart + NBLK * 16);
    float*  out     = (float*)d_out;

    hipLaunchKernelGGL(k_init,    dim3(7),         dim3(256),  0, stream,
                       bestprior, accum);
    hipLaunchKernelGGL(k_overlap, dim3(NBLK),      dim3(256),  0, stream,
                       boxes, priors, overlap, objfor, bestprior);
    hipLaunchKernelGGL(k_force,   dim3(1),         dim3(64),   0, stream,
                       bestprior, overlap, objfor);
    hipLaunchKernelGGL(k_main,    dim3(NBLK),      dim3(256),  0, stream,
                       locs, scores, boxes, labels, priors, overlap, objfor,
                       neg, pc_conf, pc_loc, pc_npos);
    hipLaunchKernelGGL(k_reduce,  dim3(BB + 1),    dim3(256),  0, stream,
                       pc_conf, pc_loc, pc_npos, n_pos, accum);
    hipLaunchKernelGGL(k_topk,    dim3(BB),        dim3(1024), 0, stream,
                       neg, n_pos, accum);
    hipLaunchKernelGGL(k_final,   dim3(1),         dim3(64),   0, stream,
                       n_pos, accum, out);
}

// Round 4
// 162.818 us; speedup vs baseline: 1.8403x; 1.0404x over previous
//
#include <hip/hip_runtime.h>
#include <hip/hip_bf16.h>
#include <float.h>

#define BB   32
#define PP   16384
#define NOBJ 50
#define NCLS 21
#define PBLK 64   // blocks of 256 priors per image (P/256)
#define NBLK (BB * PBLK)

// ---------------- workspace layout ----------------
// [0]       u64   bestprior[BB*NOBJ]     (12800 B) packed (iou_bits<<32)|(~p)
// [12800]   int   n_pos[BB]              (128 B)
// [12928]   double accum[3]              (24 B)  0:conf_pos 1:loc_sum 2:hard_neg
// [16384]   float overlap[BB*PP]         (2 MB)
// [+2MB]    int   objfor[BB*PP]          (2 MB)
// [+4MB]    float neg[BB*PP]             (2 MB)
// [+6MB]    double pc_conf[NBLK]         (16 KB)
// [..]      double pc_loc[NBLK]          (16 KB)
// [..]      int    pc_npos[NBLK]         (8 KB)

__global__ void k_init(unsigned long long* __restrict__ bestprior,
                       double* __restrict__ accum) {
    int i = blockIdx.x * 256 + threadIdx.x;
    if (i < BB * NOBJ) bestprior[i] = 0xFFFFFFFFull;  // iou=0, prior=0
    if (i < 3) accum[i] = 0.0;
}

__global__ __launch_bounds__(256) void k_overlap(
    const float* __restrict__ boxes, const float* __restrict__ priors,
    float* __restrict__ overlap, int* __restrict__ objfor,
    unsigned long long* __restrict__ bestprior)
{
#pragma clang fp contract(off)
    const int b  = (int)blockIdx.x >> 6;
    const int p0 = ((int)blockIdx.x & 63) << 8;
    const int t  = (int)threadIdx.x;
    const int p  = p0 + t;

    __shared__ float4 sbox[NOBJ];
    __shared__ float  sarea[NOBJ];
    __shared__ unsigned long long sbest[NOBJ];

    if (t < NOBJ) {
        float4 bx = reinterpret_cast<const float4*>(boxes)[b * NOBJ + t];
        sbox[t]  = bx;
        sarea[t] = (bx.z - bx.x) * (bx.w - bx.y);
        sbest[t] = 0xFFFFFFFFull;   // iou=0, prior=0 (matches global init)
    }
    __syncthreads();

    float4 pc = reinterpret_cast<const float4*>(priors)[p];
    float hx = pc.z / 2.0f, hy = pc.w / 2.0f;
    float px0 = pc.x - hx, py0 = pc.y - hy;
    float px1 = pc.x + hx, py1 = pc.y + hy;
    float areab = (px1 - px0) * (py1 - py0);

    const unsigned inv = 0xFFFFFFFFu - (unsigned)p;

    float best = -1.0f; int bestn = 0;
    for (int n = 0; n < NOBJ; ++n) {
        float4 bx = sbox[n];
        float ltx = fmaxf(bx.x, px0), lty = fmaxf(bx.y, py0);
        float rbx = fminf(bx.z, px1), rby = fminf(bx.w, py1);
        float dx = fmaxf(rbx - ltx, 0.0f);
        float dy = fmaxf(rby - lty, 0.0f);
        float inter = dx * dy;
        // fast div: ~2ulp; only exact ties / hairline 0.5-crossings can flip,
        // each worth ~1e-3 on the loss vs 0.43 threshold
        float iou = __fdividef(inter, (sarea[n] + areab) - inter);
        if (iou > best) { best = iou; bestn = n; }   // first-max wins (strict >)
        // per-object best prior: broadcast LDS read prefilter, atomic only on
        // improvement. sbest is monotone -> stale read is a benign extra atomic.
        unsigned long long key =
            ((unsigned long long)__float_as_uint(iou) << 32) |
            (unsigned long long)inv;
        if (key > sbest[n]) atomicMax(&sbest[n], key);
    }
    overlap[b * PP + p] = best;
    objfor[b * PP + p]  = bestn;
    __syncthreads();

    if (t < NOBJ) {
        unsigned long long k2 = sbest[t];
        if (k2 > 0xFFFFFFFFull)                      // block saw a positive iou
            atomicMax(&bestprior[b * NOBJ + t], k2);
    }
}

__global__ void k_force(const unsigned long long* __restrict__ bestprior,
                        float* __restrict__ overlap, int* __restrict__ objfor) {
    int b = (int)threadIdx.x;
    if (b >= BB) return;
    for (int n = 0; n < NOBJ; ++n) {                 // ascending n -> last wins
        unsigned long long pk = bestprior[b * NOBJ + n];
        int p = (int)(0xFFFFFFFFu - (unsigned)(pk & 0xFFFFFFFFull));
        objfor[b * PP + p]  = n;
        overlap[b * PP + p] = 1.0f;
    }
}

__global__ __launch_bounds__(256) void k_main(
    const float* __restrict__ locs, const float* __restrict__ scores,
    const float* __restrict__ boxes, const int* __restrict__ labels,
    const float* __restrict__ priors, const float* __restrict__ overlap,
    const int* __restrict__ objfor, float* __restrict__ neg,
    double* __restrict__ pc_conf, double* __restrict__ pc_loc,
    int* __restrict__ pc_npos)
{
#pragma clang fp contract(off)
    const int b   = (int)blockIdx.x >> 6;
    const int p0  = ((int)blockIdx.x & 63) << 8;
    const int t   = (int)threadIdx.x;
    const int p   = p0 + t;
    const int idx = b * PP + p;

    // stage 256x21 scores tile via coalesced float4 loads (21504 B, 16B-aligned)
    __shared__ float sls[256 * NCLS];
    __shared__ double sconf[4], sloc[4];
    __shared__ int    snp[4];
    {
        const float4* gsc = reinterpret_cast<const float4*>(
            scores + (size_t)(b * PP + p0) * NCLS);
        float4* dls = reinterpret_cast<float4*>(sls);
#pragma unroll
        for (int i = 0; i < 6; ++i) {
            int j = i * 256 + t;
            if (j < (256 * NCLS) / 4) dls[j] = gsc[j];
        }
    }
    __syncthreads();

    const int   n = objfor[idx];
    const float v = overlap[idx];
    int lbl = labels[b * NOBJ + n];
    if (v < 0.5f) lbl = 0;
    const bool pos = (lbl != 0);

    float locl1 = 0.0f;
    if (pos) {
        float4 bx = reinterpret_cast<const float4*>(boxes)[b * NOBJ + n];
        float4 pr = reinterpret_cast<const float4*>(priors)[p];
        float cx = (bx.x + bx.z) / 2.0f;
        float cy = (bx.y + bx.w) / 2.0f;
        float w  = bx.z - bx.x, h = bx.w - bx.y;
        float gx = (cx - pr.x) / (pr.z / 10.0f);
        float gy = (cy - pr.y) / (pr.w / 10.0f);
        float gw = logf(w / pr.z) * 5.0f;
        float gh = logf(h / pr.w) * 5.0f;
        float4 pl = reinterpret_cast<const float4*>(locs)[idx];
        locl1 = fabsf(pl.x - gx) + fabsf(pl.y - gy) +
                fabsf(pl.z - gw) + fabsf(pl.w - gh);
    }

    // cross-entropy via log-softmax over 21 classes (from LDS; stride 21 vs
    // 32 banks is coprime -> 2-way aliasing only, free)
    float x[NCLS];
    float m = -FLT_MAX;
#pragma unroll
    for (int c = 0; c < NCLS; ++c) { x[c] = sls[t * NCLS + c]; m = fmaxf(m, x[c]); }
    float tgt = 0.0f;
#pragma unroll
    for (int c = 0; c < NCLS; ++c) tgt = (c == lbl) ? x[c] : tgt;
    float s = 0.0f;
#pragma unroll
    for (int c = 0; c < NCLS; ++c) s += expf(x[c] - m);
    float ce = (logf(s) + m) - tgt;

    neg[idx] = pos ? 0.0f : ce;

    // wave reductions -> per-block partials (NO global atomics)
    float cp = pos ? ce : 0.0f;
    unsigned long long bal = __ballot(pos);
    float s1 = cp, s2 = locl1;
    for (int o = 32; o > 0; o >>= 1) {
        s1 += __shfl_down(s1, o, 64);
        s2 += __shfl_down(s2, o, 64);
    }
    if ((t & 63) == 0) {
        int w = t >> 6;
        sconf[w] = (double)s1;
        sloc[w]  = (double)s2;
        snp[w]   = (int)__popcll(bal);
    }
    __syncthreads();
    if (t == 0) {
        pc_conf[blockIdx.x] = sconf[0] + sconf[1] + sconf[2] + sconf[3];
        pc_loc[blockIdx.x]  = sloc[0] + sloc[1] + sloc[2] + sloc[3];
        pc_npos[blockIdx.x] = snp[0] + snp[1] + snp[2] + snp[3];
    }
}

// blocks 0..BB-1: n_pos[b] = sum of that image's 64 block partials
// block BB: accum[0] = sum pc_conf, accum[1] = sum pc_loc
__global__ __launch_bounds__(256) void k_reduce(
    const double* __restrict__ pc_conf, const double* __restrict__ pc_loc,
    const int* __restrict__ pc_npos, int* __restrict__ n_pos,
    double* __restrict__ accum)
{
    const int t = (int)threadIdx.x;
    if ((int)blockIdx.x < BB) {
        const int b = (int)blockIdx.x;
        int v = (t < PBLK) ? pc_npos[b * PBLK + t] : 0;
        for (int o = 32; o > 0; o >>= 1) v += __shfl_down(v, o, 64);
        if (t == 0) n_pos[b] = v;
    } else {
        __shared__ double sa[4], sb[4];
        double a = 0.0, c = 0.0;
        for (int i = t; i < NBLK; i += 256) { a += pc_conf[i]; c += pc_loc[i]; }
        for (int o = 32; o > 0; o >>= 1) {
            a += __shfl_down(a, o, 64);
            c += __shfl_down(c, o, 64);
        }
        if ((t & 63) == 0) { sa[t >> 6] = a; sb[t >> 6] = c; }
        __syncthreads();
        if (t == 0) {
            accum[0] = sa[0] + sa[1] + sa[2] + sa[3];
            accum[1] = sb[0] + sb[1] + sb[2] + sb[3];
        }
    }
}

// exact sum of top-K of neg[b,:] via 4x8-bit radix select (ce >= 0 so
// float bit pattern is order-preserving as uint). All passes run from LDS.
__global__ __launch_bounds__(1024) void k_topk(
    const float* __restrict__ neg, const int* __restrict__ n_pos,
    double* __restrict__ accum)
{
    const int b = (int)blockIdx.x;
    const int t = (int)threadIdx.x;
    const int wid = t >> 6;

    __shared__ float sval[PP];                 // 64 KB staged image
    __shared__ unsigned shist[16 * 257];       // per-wave padded histograms
    __shared__ unsigned scomb[256];
    __shared__ unsigned s_bb, s_above;
    __shared__ float swave[16];

    // stage neg[b,:] coalesced
    {
        const float4* g = reinterpret_cast<const float4*>(neg + (size_t)b * PP);
        float4* d = reinterpret_cast<float4*>(sval);
#pragma unroll
        for (int i = 0; i < PP / 4 / 1024; ++i)
            d[i * 1024 + t] = g[i * 1024 + t];
    }

    long long K = 3LL * (long long)n_pos[b];
    if (K > PP) K = PP;
    unsigned remaining = (unsigned)K;
    unsigned prefix = 0, mask = 0;
    float mySum = 0.0f;
    __syncthreads();

    for (int shift = 24; shift >= 0; shift -= 8) {
        for (int i = t; i < 16 * 257; i += 1024) shist[i] = 0;
        __syncthreads();
#pragma unroll
        for (int i = 0; i < PP / 1024; ++i) {
            unsigned u = __float_as_uint(sval[i * 1024 + t]);
            if ((u & mask) == prefix)
                atomicAdd(&shist[wid * 257 + ((u >> shift) & 255u)], 1u);
        }
        __syncthreads();
        if (t < 256) {
            unsigned c = 0;
#pragma unroll
            for (int w = 0; w < 16; ++w) c += shist[w * 257 + t];
            scomb[t] = c;
        }
        __syncthreads();
        if (t == 0) {
            unsigned cum = 0, bb = 0, above = 0;
            for (int bin = 255; bin >= 0; --bin) {
                unsigned c = scomb[bin];
                if (cum + c >= remaining) { bb = (unsigned)bin; above = cum; break; }
                cum += c;
            }
            s_bb = bb; s_above = above;
        }
        __syncthreads();
        unsigned bb = s_bb;
#pragma unroll
        for (int i = 0; i < PP / 1024; ++i) {
            unsigned u = __float_as_uint(sval[i * 1024 + t]);
            if ((u & mask) == prefix && ((u >> shift) & 255u) > bb)
                mySum += __uint_as_float(u);
        }
        remaining -= s_above;
        prefix |= bb << shift;
        mask   |= 255u << shift;
        __syncthreads();
    }

    float s = mySum;
    for (int o = 32; o > 0; o >>= 1) s += __shfl_down(s, o, 64);
    if ((t & 63) == 0) swave[wid] = s;
    __syncthreads();
    if (t == 0) {
        float tot = 0.0f;
        for (int w = 0; w < 16; ++w) tot += swave[w];
        if (remaining) tot += (float)remaining * __uint_as_float(prefix);
        atomicAdd(&accum[2], (double)tot);   // 32 blocks total: negligible
    }
}

__global__ void k_final(const int* __restrict__ n_pos,
                        const double* __restrict__ accum,
                        float* __restrict__ out) {
    if (threadIdx.x == 0 && blockIdx.x == 0) {
        int tot = 0;
        for (int b = 0; b < BB; ++b) tot += n_pos[b];
        double npt  = (double)tot;
        double conf = (accum[0] + accum[2]) / npt;
        double loc  = accum[1] / (npt * 4.0);
        out[0] = (float)(conf + loc);
    }
}

extern "C" void kernel_launch(void* const* d_in, const int* in_sizes, int n_in,
                              void* d_out, int out_size, void* d_ws, size_t ws_size,
                              hipStream_t stream) {
    const float* locs   = (const float*)d_in[0];
    const float* scores = (const float*)d_in[1];
    const float* boxes  = (const float*)d_in[2];
    const int*   labels = (const int*)d_in[3];
    const float* priors = (const float*)d_in[4];

    char* ws = (char*)d_ws;
    unsigned long long* bestprior = (unsigned long long*)ws;
    int*    n_pos   = (int*)(ws + 12800);
    double* accum   = (double*)(ws + 12928);
    float*  overlap = (float*)(ws + 16384);
    int*    objfor  = (int*)(ws + 16384 + (size_t)BB * PP * 4);
    float*  neg     = (float*)(ws + 16384 + (size_t)BB * PP * 8);
    char*   ppart   = ws + 16384 + (size_t)BB * PP * 12;
    double* pc_conf = (double*)ppart;
    double* pc_loc  = (double*)(ppart + NBLK * 8);
    int*    pc_npos = (int*)(ppart + NBLK * 16);
    float*  out     = (float*)d_out;

    hipLaunchKernelGGL(k_init,    dim3(7),         dim3(256),  0, stream,
                       bestprior, accum);
    hipLaunchKernelGGL(k_overlap, dim3(NBLK),      dim3(256),  0, stream,
                       boxes, priors, overlap, objfor, bestprior);
    hipLaunchKernelGGL(k_force,   dim3(1),         dim3(64),   0, stream,
                       bestprior, overlap, objfor);
    hipLaunchKernelGGL(k_main,    dim3(NBLK),      dim3(256),  0, stream,
                       locs, scores, boxes, labels, priors, overlap, objfor,
                       neg, pc_conf, pc_loc, pc_npos);
    hipLaunchKernelGGL(k_reduce,  dim3(BB + 1),    dim3(256),  0, stream,
                       pc_conf, pc_loc, pc_npos, n_pos, accum);
    hipLaunchKernelGGL(k_topk,    dim3(BB),        dim3(1024), 0, stream,
                       neg, n_pos, accum);
    hipLaunchKernelGGL(k_final,   dim3(1),         dim3(64),   0, stream,
                       n_pos, accum, out);
}